// Round 1
// baseline (622.983 us; speedup 1.0000x reference)
//
#include <hip/hip_runtime.h>
#include <hip/hip_bf16.h>

#define GRID 64
#define N_VOX (GRID * GRID * GRID)   // 262144
#define NCH 64

// ---------------- init: fill output with -inf sentinel ----------------
__global__ void gp_init_kernel(float4* __restrict__ out4, int n4) {
    int i = blockIdx.x * blockDim.x + threadIdx.x;
    if (i < n4) {
        float4 v;
        v.x = -INFINITY; v.y = -INFINITY; v.z = -INFINITY; v.w = -INFINITY;
        out4[i] = v;
    }
}

// ---------------- float atomic max via int bit tricks ----------------
// Valid for all finite floats and the -inf sentinel; no NaNs in input.
__device__ __forceinline__ void atomic_max_float(float* addr, float value) {
    if (value >= 0.0f) {
        atomicMax((int*)addr, __float_as_int(value));
    } else {
        atomicMin((unsigned int*)addr, __float_as_uint(value));
    }
}

// ---------------- scatter: one thread per (point, channel) ----------------
__global__ void gp_scatter_kernel(const int* __restrict__ verts,
                                  const float* __restrict__ feats,
                                  float* __restrict__ out,
                                  int n_pts) {
    unsigned int t = blockIdx.x * blockDim.x + threadIdx.x;
    unsigned int p = t >> 6;   // point index
    unsigned int c = t & 63;   // channel index
    if (p >= (unsigned int)n_pts) return;

    // 64 lanes of a wave share one point -> these loads broadcast
    int x = verts[3 * p + 0] >> 2;   // coords in [0,256), floor-div by 4
    int y = verts[3 * p + 1] >> 2;
    int z = verts[3 * p + 2] >> 2;
    unsigned int vox = ((unsigned int)x << 12) | ((unsigned int)y << 6) | (unsigned int)z;

    float v = feats[(size_t)p * NCH + c];          // coalesced
    atomic_max_float(out + (size_t)vox * NCH + c, v);  // coalesced within wave
}

// ---------------- finalize: empty voxels (-inf) -> 0 ----------------
__global__ void gp_finalize_kernel(float4* __restrict__ out4, int n4) {
    int i = blockIdx.x * blockDim.x + threadIdx.x;
    if (i < n4) {
        float4 v = out4[i];
        if (__float_as_uint(v.x) == 0xFF800000u) v.x = 0.0f;
        if (__float_as_uint(v.y) == 0xFF800000u) v.y = 0.0f;
        if (__float_as_uint(v.z) == 0xFF800000u) v.z = 0.0f;
        if (__float_as_uint(v.w) == 0xFF800000u) v.w = 0.0f;
        out4[i] = v;
    }
}

extern "C" void kernel_launch(void* const* d_in, const int* in_sizes, int n_in,
                              void* d_out, int out_size, void* d_ws, size_t ws_size,
                              hipStream_t stream) {
    const int*   verts = (const int*)d_in[0];    // [N,3] int32
    const float* feats = (const float*)d_in[1];  // [N,64] fp32
    float*       out   = (float*)d_out;          // [N_VOX*64] fp32

    const int n_pts = in_sizes[0] / 3;           // 1,000,000
    const int n_out = out_size;                  // N_VOX * 64 = 16,777,216
    const int n4    = n_out / 4;

    // 1) init output to -inf
    {
        const int block = 256;
        const int grid  = (n4 + block - 1) / block;
        gp_init_kernel<<<grid, block, 0, stream>>>((float4*)out, n4);
    }

    // 2) scatter atomic max, one thread per (point, channel)
    {
        const int block = 256;
        const long long total = (long long)n_pts * NCH;
        const int grid = (int)((total + block - 1) / block);
        gp_scatter_kernel<<<grid, block, 0, stream>>>(verts, feats, out, n_pts);
    }

    // 3) finalize: -inf -> 0
    {
        const int block = 256;
        const int grid  = (n4 + block - 1) / block;
        gp_finalize_kernel<<<grid, block, 0, stream>>>((float4*)out, n4);
    }
}

// Round 2
// 579.809 us; speedup vs baseline: 1.0745x; 1.0745x over previous
//
#include <hip/hip_runtime.h>
#include <hip/hip_bf16.h>

#define GRID 64
#define N_VOX (GRID * GRID * GRID)   // 262144
#define NCH 64

// ============================================================================
// Sort-based path: histogram -> scan -> scatter indices -> gather max
// ============================================================================

// ---- k1: voxel id per point + histogram --------------------------------
__global__ void k_hist(const int* __restrict__ verts, int* __restrict__ vox,
                       int* __restrict__ counts, int n) {
    int p = blockIdx.x * blockDim.x + threadIdx.x;
    if (p >= n) return;
    int x = verts[3 * p + 0] >> 2;
    int y = verts[3 * p + 1] >> 2;
    int z = verts[3 * p + 2] >> 2;
    int v = (x << 12) | (y << 6) | z;
    vox[p] = v;
    atomicAdd(&counts[v], 1);
}

// ---- k2a: block-local exclusive scan (1024 elems/block, 256 blocks) ----
__global__ void __launch_bounds__(1024)
k_scan1(const int* __restrict__ counts, int* __restrict__ offsets,
        int* __restrict__ bsum) {
    int g = blockIdx.x * 1024 + threadIdx.x;
    int v = counts[g];
    int lane = threadIdx.x & 63;
    int wid  = threadIdx.x >> 6;      // 0..15

    // wave-level inclusive scan
    int incl = v;
    #pragma unroll
    for (int off = 1; off < 64; off <<= 1) {
        int u = __shfl_up(incl, off);
        if (lane >= off) incl += u;
    }

    __shared__ int wsum[16];
    if (lane == 63) wsum[wid] = incl;
    __syncthreads();

    if (wid == 0) {
        int s  = (lane < 16) ? wsum[lane] : 0;
        int si = s;
        #pragma unroll
        for (int off = 1; off < 16; off <<= 1) {
            int u = __shfl_up(si, off);
            if (lane >= off) si += u;
        }
        if (lane < 16) wsum[lane] = si - s;   // exclusive wave base
    }
    __syncthreads();

    offsets[g] = wsum[wid] + incl - v;        // block-local exclusive scan
    if (threadIdx.x == 1023) bsum[blockIdx.x] = wsum[15] + incl;  // block total
}

// ---- k2b: exclusive scan of the 256 block sums (single block) ----------
__global__ void __launch_bounds__(256) k_scan2(int* __restrict__ bsum) {
    int t = threadIdx.x;
    int v = bsum[t];
    int lane = t & 63;
    int wid  = t >> 6;    // 0..3
    int incl = v;
    #pragma unroll
    for (int off = 1; off < 64; off <<= 1) {
        int u = __shfl_up(incl, off);
        if (lane >= off) incl += u;
    }
    __shared__ int ws[4];
    if (lane == 63) ws[wid] = incl;
    __syncthreads();
    int base = 0;
    for (int i = 0; i < wid; i++) base += ws[i];
    bsum[t] = base + incl - v;                // exclusive scan result
}

// ---- k3: scatter point indices into bucket order -----------------------
__global__ void k_scatter_idx(const int* __restrict__ vox,
                              int* __restrict__ offsets,        // block-local excl, mutated
                              const int* __restrict__ bsum,     // scanned block bases
                              int* __restrict__ sorted_idx, int n) {
    int p = blockIdx.x * blockDim.x + threadIdx.x;
    if (p >= n) return;
    int v = vox[p];
    int local = atomicAdd(&offsets[v], 1);
    sorted_idx[local + bsum[v >> 10]] = p;
}

// ---- k4: gather max — one wave per voxel, lane = channel ---------------
__global__ void __launch_bounds__(256)
k_gather(const int* __restrict__ sorted_idx,
         const int* __restrict__ offsets,     // post-scatter: local excl + count
         const int* __restrict__ counts,
         const int* __restrict__ bsum,
         const float* __restrict__ feats,
         float* __restrict__ out) {
    unsigned int t    = blockIdx.x * blockDim.x + threadIdx.x;
    unsigned int wave = t >> 6;               // voxel id
    unsigned int lane = t & 63;               // channel
    if (wave >= N_VOX) return;

    int cnt   = counts[wave];
    int end   = offsets[wave] + bsum[wave >> 10];  // = global start + cnt
    int start = end - cnt;

    float acc = -INFINITY;
    for (int i = start; i < end; i++) {
        int p = sorted_idx[i];                              // wave-uniform addr
        acc = fmaxf(acc, feats[(size_t)p * NCH + lane]);    // 256B coalesced
    }
    out[(size_t)wave * NCH + lane] = (cnt > 0) ? acc : 0.0f;
}

// ============================================================================
// Fallback atomic path (round-1 code) if ws_size is too small
// ============================================================================
__global__ void gp_init_kernel(float4* __restrict__ out4, int n4) {
    int i = blockIdx.x * blockDim.x + threadIdx.x;
    if (i < n4) {
        float4 v; v.x = v.y = v.z = v.w = -INFINITY;
        out4[i] = v;
    }
}
__device__ __forceinline__ void atomic_max_float(float* addr, float value) {
    if (value >= 0.0f) atomicMax((int*)addr, __float_as_int(value));
    else               atomicMin((unsigned int*)addr, __float_as_uint(value));
}
__global__ void gp_scatter_kernel(const int* __restrict__ verts,
                                  const float* __restrict__ feats,
                                  float* __restrict__ out, int n_pts) {
    unsigned int t = blockIdx.x * blockDim.x + threadIdx.x;
    unsigned int p = t >> 6, c = t & 63;
    if (p >= (unsigned int)n_pts) return;
    int x = verts[3 * p + 0] >> 2, y = verts[3 * p + 1] >> 2, z = verts[3 * p + 2] >> 2;
    unsigned int vox = ((unsigned int)x << 12) | ((unsigned int)y << 6) | (unsigned int)z;
    atomic_max_float(out + (size_t)vox * NCH + c, feats[(size_t)p * NCH + c]);
}
__global__ void gp_finalize_kernel(float4* __restrict__ out4, int n4) {
    int i = blockIdx.x * blockDim.x + threadIdx.x;
    if (i < n4) {
        float4 v = out4[i];
        if (__float_as_uint(v.x) == 0xFF800000u) v.x = 0.0f;
        if (__float_as_uint(v.y) == 0xFF800000u) v.y = 0.0f;
        if (__float_as_uint(v.z) == 0xFF800000u) v.z = 0.0f;
        if (__float_as_uint(v.w) == 0xFF800000u) v.w = 0.0f;
        out4[i] = v;
    }
}

// ============================================================================
extern "C" void kernel_launch(void* const* d_in, const int* in_sizes, int n_in,
                              void* d_out, int out_size, void* d_ws, size_t ws_size,
                              hipStream_t stream) {
    const int*   verts = (const int*)d_in[0];    // [N,3] int32
    const float* feats = (const float*)d_in[1];  // [N,64] fp32
    float*       out   = (float*)d_out;          // [N_VOX*64] fp32

    const int n_pts = in_sizes[0] / 3;           // 1,000,000
    const int n_out = out_size;                  // 16,777,216

    // workspace layout (all int32)
    const size_t need = (size_t)n_pts * 4        // vox
                      + (size_t)n_pts * 4        // sorted_idx
                      + (size_t)N_VOX * 4        // counts
                      + (size_t)N_VOX * 4        // offsets
                      + 256 * 4;                 // bsum

    if (ws_size >= need) {
        char* w = (char*)d_ws;
        int* vox        = (int*)w;               w += (size_t)n_pts * 4;
        int* sorted_idx = (int*)w;               w += (size_t)n_pts * 4;
        int* counts     = (int*)w;               w += (size_t)N_VOX * 4;
        int* offsets    = (int*)w;               w += (size_t)N_VOX * 4;
        int* bsum       = (int*)w;

        hipMemsetAsync(counts, 0, (size_t)N_VOX * 4, stream);

        {   // histogram + voxel ids
            const int block = 256;
            const int grid  = (n_pts + block - 1) / block;
            k_hist<<<grid, block, 0, stream>>>(verts, vox, counts, n_pts);
        }
        {   // hierarchical exclusive scan
            k_scan1<<<N_VOX / 1024, 1024, 0, stream>>>(counts, offsets, bsum);
            k_scan2<<<1, 256, 0, stream>>>(bsum);
        }
        {   // scatter indices
            const int block = 256;
            const int grid  = (n_pts + block - 1) / block;
            k_scatter_idx<<<grid, block, 0, stream>>>(vox, offsets, bsum,
                                                      sorted_idx, n_pts);
        }
        {   // gather max: one wave per voxel
            const long long total = (long long)N_VOX * 64;
            const int block = 256;
            const int grid  = (int)((total + block - 1) / block);
            k_gather<<<grid, block, 0, stream>>>(sorted_idx, offsets, counts,
                                                 bsum, feats, out);
        }
    } else {
        // fallback: atomic scatter-max
        const int n4 = n_out / 4;
        gp_init_kernel<<<(n4 + 255) / 256, 256, 0, stream>>>((float4*)out, n4);
        const long long total = (long long)n_pts * NCH;
        gp_scatter_kernel<<<(int)((total + 255) / 256), 256, 0, stream>>>(
            verts, feats, out, n_pts);
        gp_finalize_kernel<<<(n4 + 255) / 256, 256, 0, stream>>>((float4*)out, n4);
    }
}

// Round 3
// 538.260 us; speedup vs baseline: 1.1574x; 1.0772x over previous
//
#include <hip/hip_runtime.h>
#include <hip/hip_bf16.h>

#define GRID 64
#define N_VOX (GRID * GRID * GRID)   // 262144
#define NCH 64

// ============================================================================
// Sort-based path: histogram -> scan -> scatter indices -> gather max
// ============================================================================

__device__ __forceinline__ int vox_of(int x, int y, int z) {
    return ((x >> 2) << 12) | ((y >> 2) << 6) | (z >> 2);
}

// ---- k1: voxel id per point + histogram, 4 points/thread ----------------
__global__ void k_hist(const int* __restrict__ verts, int* __restrict__ vox,
                       int* __restrict__ counts, int n) {
    int t  = blockIdx.x * blockDim.x + threadIdx.x;
    int p0 = t * 4;
    if (p0 >= n) return;

    if (p0 + 4 <= n) {
        const int4* v4 = (const int4*)verts;           // 16B-aligned base
        int4 a = v4[3 * t + 0];
        int4 b = v4[3 * t + 1];
        int4 c = v4[3 * t + 2];
        int w0 = vox_of(a.x, a.y, a.z);
        int w1 = vox_of(a.w, b.x, b.y);
        int w2 = vox_of(b.z, b.w, c.x);
        int w3 = vox_of(c.y, c.z, c.w);
        ((int4*)vox)[t] = make_int4(w0, w1, w2, w3);
        atomicAdd(&counts[w0], 1);
        atomicAdd(&counts[w1], 1);
        atomicAdd(&counts[w2], 1);
        atomicAdd(&counts[w3], 1);
    } else {
        for (int p = p0; p < n; p++) {
            int w = vox_of(verts[3 * p], verts[3 * p + 1], verts[3 * p + 2]);
            vox[p] = w;
            atomicAdd(&counts[w], 1);
        }
    }
}

// ---- k2a: block-local exclusive scan (1024 elems/block, 256 blocks) ----
__global__ void __launch_bounds__(1024)
k_scan1(const int* __restrict__ counts, int* __restrict__ offsets,
        int* __restrict__ bsum) {
    int g = blockIdx.x * 1024 + threadIdx.x;
    int v = counts[g];
    int lane = threadIdx.x & 63;
    int wid  = threadIdx.x >> 6;      // 0..15

    int incl = v;
    #pragma unroll
    for (int off = 1; off < 64; off <<= 1) {
        int u = __shfl_up(incl, off);
        if (lane >= off) incl += u;
    }

    __shared__ int wsum[16];
    if (lane == 63) wsum[wid] = incl;
    __syncthreads();

    if (wid == 0) {
        int s  = (lane < 16) ? wsum[lane] : 0;
        int si = s;
        #pragma unroll
        for (int off = 1; off < 16; off <<= 1) {
            int u = __shfl_up(si, off);
            if (lane >= off) si += u;
        }
        if (lane < 16) wsum[lane] = si - s;   // exclusive wave base
    }
    __syncthreads();

    offsets[g] = wsum[wid] + incl - v;        // block-local exclusive scan
    if (threadIdx.x == 1023) bsum[blockIdx.x] = wsum[15] + incl;  // block total
}

// ---- k2b: exclusive scan of the 256 block sums (single block) ----------
__global__ void __launch_bounds__(256) k_scan2(int* __restrict__ bsum) {
    int t = threadIdx.x;
    int v = bsum[t];
    int lane = t & 63;
    int wid  = t >> 6;    // 0..3
    int incl = v;
    #pragma unroll
    for (int off = 1; off < 64; off <<= 1) {
        int u = __shfl_up(incl, off);
        if (lane >= off) incl += u;
    }
    __shared__ int ws[4];
    if (lane == 63) ws[wid] = incl;
    __syncthreads();
    int base = 0;
    for (int i = 0; i < wid; i++) base += ws[i];
    bsum[t] = base + incl - v;                // exclusive scan result
}

// ---- k3: scatter point indices into bucket order, 4 points/thread ------
__global__ void k_scatter_idx(const int* __restrict__ vox,
                              int* __restrict__ offsets,     // mutated
                              const int* __restrict__ bsum,
                              int* __restrict__ sorted_idx, int n) {
    int t  = blockIdx.x * blockDim.x + threadIdx.x;
    int p0 = t * 4;
    if (p0 >= n) return;

    if (p0 + 4 <= n) {
        int4 w = ((const int4*)vox)[t];
        int l0 = atomicAdd(&offsets[w.x], 1);
        int l1 = atomicAdd(&offsets[w.y], 1);
        int l2 = atomicAdd(&offsets[w.z], 1);
        int l3 = atomicAdd(&offsets[w.w], 1);
        sorted_idx[l0 + bsum[w.x >> 10]] = p0 + 0;
        sorted_idx[l1 + bsum[w.y >> 10]] = p0 + 1;
        sorted_idx[l2 + bsum[w.z >> 10]] = p0 + 2;
        sorted_idx[l3 + bsum[w.w >> 10]] = p0 + 3;
    } else {
        for (int p = p0; p < n; p++) {
            int w = vox[p];
            int l = atomicAdd(&offsets[w], 1);
            sorted_idx[l + bsum[w >> 10]] = p;
        }
    }
}

// ---- k4: gather max — one wave per voxel, lane = channel ---------------
// Cooperative idx load (1 coalesced load per 64 points) + 4-wide unrolled
// fmax body with clamped indices (max is idempotent -> no tail loop).
__global__ void __launch_bounds__(256)
k_gather(const int* __restrict__ sorted_idx,
         const int* __restrict__ offsets,     // post-scatter: local excl + count
         const int* __restrict__ counts,
         const int* __restrict__ bsum,
         const float* __restrict__ feats,
         float* __restrict__ out) {
    unsigned int t    = blockIdx.x * blockDim.x + threadIdx.x;
    unsigned int wave = t >> 6;               // voxel id
    unsigned int lane = t & 63;               // channel
    if (wave >= N_VOX) return;

    int cnt = counts[wave];
    if (cnt == 0) {
        out[(size_t)wave * NCH + lane] = 0.0f;
        return;
    }
    int end   = offsets[wave] + bsum[wave >> 10];  // global end
    int start = end - cnt;

    float a0 = -INFINITY, a1 = -INFINITY, a2 = -INFINITY, a3 = -INFINITY;
    for (int base = start; base < end; base += 64) {
        int nb = min(64, end - base);
        // one coalesced load covers up to 64 indices; clamp dup for lanes>=nb
        int pv = sorted_idx[base + min((int)lane, nb - 1)];
        for (int j = 0; j < nb; j += 4) {
            int p0 = __shfl(pv, min(j + 0, nb - 1));
            int p1 = __shfl(pv, min(j + 1, nb - 1));
            int p2 = __shfl(pv, min(j + 2, nb - 1));
            int p3 = __shfl(pv, min(j + 3, nb - 1));
            float f0 = feats[(size_t)p0 * NCH + lane];
            float f1 = feats[(size_t)p1 * NCH + lane];
            float f2 = feats[(size_t)p2 * NCH + lane];
            float f3 = feats[(size_t)p3 * NCH + lane];
            a0 = fmaxf(a0, f0);
            a1 = fmaxf(a1, f1);
            a2 = fmaxf(a2, f2);
            a3 = fmaxf(a3, f3);
        }
    }
    out[(size_t)wave * NCH + lane] = fmaxf(fmaxf(a0, a1), fmaxf(a2, a3));
}

// ============================================================================
extern "C" void kernel_launch(void* const* d_in, const int* in_sizes, int n_in,
                              void* d_out, int out_size, void* d_ws, size_t ws_size,
                              hipStream_t stream) {
    const int*   verts = (const int*)d_in[0];    // [N,3] int32
    const float* feats = (const float*)d_in[1];  // [N,64] fp32
    float*       out   = (float*)d_out;          // [N_VOX*64] fp32

    const int n_pts = in_sizes[0] / 3;           // 1,000,000

    char* w = (char*)d_ws;
    int* vox        = (int*)w;               w += (size_t)n_pts * 4;
    int* sorted_idx = (int*)w;               w += (size_t)n_pts * 4;
    int* counts     = (int*)w;               w += (size_t)N_VOX * 4;
    int* offsets    = (int*)w;               w += (size_t)N_VOX * 4;
    int* bsum       = (int*)w;

    hipMemsetAsync(counts, 0, (size_t)N_VOX * 4, stream);

    {   // histogram + voxel ids (4 points/thread)
        const int block = 256;
        const int nthr  = (n_pts + 3) / 4;
        const int grid  = (nthr + block - 1) / block;
        k_hist<<<grid, block, 0, stream>>>(verts, vox, counts, n_pts);
    }
    {   // hierarchical exclusive scan
        k_scan1<<<N_VOX / 1024, 1024, 0, stream>>>(counts, offsets, bsum);
        k_scan2<<<1, 256, 0, stream>>>(bsum);
    }
    {   // scatter indices (4 points/thread)
        const int block = 256;
        const int nthr  = (n_pts + 3) / 4;
        const int grid  = (nthr + block - 1) / block;
        k_scatter_idx<<<grid, block, 0, stream>>>(vox, offsets, bsum,
                                                  sorted_idx, n_pts);
    }
    {   // gather max: one wave per voxel
        const long long total = (long long)N_VOX * 64;
        const int block = 256;
        const int grid  = (int)((total + block - 1) / block);
        k_gather<<<grid, block, 0, stream>>>(sorted_idx, offsets, counts,
                                             bsum, feats, out);
    }
}

// Round 4
// 484.497 us; speedup vs baseline: 1.2858x; 1.1110x over previous
//
#include <hip/hip_runtime.h>
#include <hip/hip_bf16.h>

#define GRID 64
#define N_VOX (GRID * GRID * GRID)   // 262144
#define NCH 64

// ============================================================================
// Pipeline: hist -> bsum -> scan2 -> scanfinal(meta) -> scatter_idx -> gather
// ============================================================================

__device__ __forceinline__ int vox_of(int x, int y, int z) {
    return ((x >> 2) << 12) | ((y >> 2) << 6) | (z >> 2);
}

// ---- k1: voxel id per point + histogram, 4 points/thread ----------------
__global__ void k_hist(const int* __restrict__ verts, int* __restrict__ vox,
                       int* __restrict__ counts, int n) {
    int t  = blockIdx.x * blockDim.x + threadIdx.x;
    int p0 = t * 4;
    if (p0 >= n) return;

    if (p0 + 4 <= n) {
        const int4* v4 = (const int4*)verts;
        int4 a = v4[3 * t + 0];
        int4 b = v4[3 * t + 1];
        int4 c = v4[3 * t + 2];
        int w0 = vox_of(a.x, a.y, a.z);
        int w1 = vox_of(a.w, b.x, b.y);
        int w2 = vox_of(b.z, b.w, c.x);
        int w3 = vox_of(c.y, c.z, c.w);
        ((int4*)vox)[t] = make_int4(w0, w1, w2, w3);
        atomicAdd(&counts[w0], 1);
        atomicAdd(&counts[w1], 1);
        atomicAdd(&counts[w2], 1);
        atomicAdd(&counts[w3], 1);
    } else {
        for (int p = p0; p < n; p++) {
            int w = vox_of(verts[3 * p], verts[3 * p + 1], verts[3 * p + 2]);
            vox[p] = w;
            atomicAdd(&counts[w], 1);
        }
    }
}

// ---- k2a: per-1024-chunk sums (256 chunks) ------------------------------
__global__ void __launch_bounds__(256)
k_bsum(const int* __restrict__ counts, int* __restrict__ bsum) {
    int b = blockIdx.x;            // 0..255
    int t = threadIdx.x;           // 0..255
    int4 c = ((const int4*)counts)[b * 256 + t];
    int s = c.x + c.y + c.z + c.w;
    #pragma unroll
    for (int off = 32; off; off >>= 1) s += __shfl_down(s, off);
    __shared__ int ws[4];
    int lane = t & 63, wid = t >> 6;
    if (lane == 0) ws[wid] = s;
    __syncthreads();
    if (t == 0) bsum[b] = ws[0] + ws[1] + ws[2] + ws[3];
}

// ---- k2b: exclusive scan of the 256 chunk sums (single block) ----------
__global__ void __launch_bounds__(256) k_scan2(int* __restrict__ bsum) {
    int t = threadIdx.x;
    int v = bsum[t];
    int lane = t & 63;
    int wid  = t >> 6;    // 0..3
    int incl = v;
    #pragma unroll
    for (int off = 1; off < 64; off <<= 1) {
        int u = __shfl_up(incl, off);
        if (lane >= off) incl += u;
    }
    __shared__ int ws[4];
    if (lane == 63) ws[wid] = incl;
    __syncthreads();
    int base = 0;
    for (int i = 0; i < wid; i++) base += ws[i];
    bsum[t] = base + incl - v;                // exclusive scan result
}

// ---- k2c: local scan + chunk base -> meta(start,end) + mutable copy ----
__global__ void __launch_bounds__(1024)
k_scanfinal(const int* __restrict__ counts, const int* __restrict__ bsum,
            int2* __restrict__ meta, int* __restrict__ gmut) {
    int g = blockIdx.x * 1024 + threadIdx.x;
    int v = counts[g];
    int lane = threadIdx.x & 63;
    int wid  = threadIdx.x >> 6;      // 0..15

    int incl = v;
    #pragma unroll
    for (int off = 1; off < 64; off <<= 1) {
        int u = __shfl_up(incl, off);
        if (lane >= off) incl += u;
    }
    __shared__ int wsum[16];
    if (lane == 63) wsum[wid] = incl;
    __syncthreads();
    if (wid == 0) {
        int s  = (lane < 16) ? wsum[lane] : 0;
        int si = s;
        #pragma unroll
        for (int off = 1; off < 16; off <<= 1) {
            int u = __shfl_up(si, off);
            if (lane >= off) si += u;
        }
        if (lane < 16) wsum[lane] = si - s;   // exclusive wave base
    }
    __syncthreads();

    int start = bsum[blockIdx.x] + wsum[wid] + incl - v;
    meta[g] = make_int2(start, start + v);
    gmut[g] = start;
}

// ---- k3: scatter point indices into bucket order, 4 points/thread ------
__global__ void k_scatter_idx(const int* __restrict__ vox,
                              int* __restrict__ gmut,       // mutated
                              int* __restrict__ sorted_idx, int n) {
    int t  = blockIdx.x * blockDim.x + threadIdx.x;
    int p0 = t * 4;
    if (p0 >= n) return;

    if (p0 + 4 <= n) {
        int4 w = ((const int4*)vox)[t];
        int l0 = atomicAdd(&gmut[w.x], 1);
        int l1 = atomicAdd(&gmut[w.y], 1);
        int l2 = atomicAdd(&gmut[w.z], 1);
        int l3 = atomicAdd(&gmut[w.w], 1);
        sorted_idx[l0] = p0 + 0;
        sorted_idx[l1] = p0 + 1;
        sorted_idx[l2] = p0 + 2;
        sorted_idx[l3] = p0 + 3;
    } else {
        for (int p = p0; p < n; p++) {
            int w = vox[p];
            sorted_idx[atomicAdd(&gmut[w], 1)] = p;
        }
    }
}

// ---- k4: gather max — 16 lanes per voxel (float4/lane), 4 voxels/wave --
__device__ __forceinline__ float4 max4(float4 a, float4 b) {
    float4 r;
    r.x = fmaxf(a.x, b.x); r.y = fmaxf(a.y, b.y);
    r.z = fmaxf(a.z, b.z); r.w = fmaxf(a.w, b.w);
    return r;
}

__global__ void __launch_bounds__(256)
k_gather(const int* __restrict__ sorted_idx,
         const int2* __restrict__ meta,
         const float4* __restrict__ feats4,   // [N, 16] float4
         float4* __restrict__ out4) {         // [N_VOX, 16] float4
    unsigned int t   = blockIdx.x * 256 + threadIdx.x;
    unsigned int vxl = t >> 4;                // voxel id
    unsigned int sub = t & 15;                // channel quad

    int2 se  = meta[vxl];                     // one 8B broadcast load
    int  cnt = se.y - se.x;

    if (cnt == 0) {
        out4[(size_t)vxl * 16 + sub] = make_float4(0.f, 0.f, 0.f, 0.f);
        return;
    }

    int lane  = threadIdx.x & 63;
    int lbase = lane & 48;                    // base lane of this 16-group

    float4 a0 = make_float4(-INFINITY, -INFINITY, -INFINITY, -INFINITY);
    float4 a1 = a0, a2 = a0, a3 = a0;

    for (int base = se.x; base < se.y; base += 16) {
        int nb = min(16, se.y - base);
        // 16 indices per group in one coalesced load (clamped duplicates)
        int pv = sorted_idx[base + min((int)sub, nb - 1)];
        for (int j = 0; j < nb; j += 4) {
            int p0 = __shfl(pv, lbase + min(j + 0, nb - 1));
            int p1 = __shfl(pv, lbase + min(j + 1, nb - 1));
            int p2 = __shfl(pv, lbase + min(j + 2, nb - 1));
            int p3 = __shfl(pv, lbase + min(j + 3, nb - 1));
            float4 f0 = feats4[(size_t)p0 * 16 + sub];
            float4 f1 = feats4[(size_t)p1 * 16 + sub];
            float4 f2 = feats4[(size_t)p2 * 16 + sub];
            float4 f3 = feats4[(size_t)p3 * 16 + sub];
            a0 = max4(a0, f0);
            a1 = max4(a1, f1);
            a2 = max4(a2, f2);
            a3 = max4(a3, f3);
        }
    }
    out4[(size_t)vxl * 16 + sub] = max4(max4(a0, a1), max4(a2, a3));
}

// ============================================================================
extern "C" void kernel_launch(void* const* d_in, const int* in_sizes, int n_in,
                              void* d_out, int out_size, void* d_ws, size_t ws_size,
                              hipStream_t stream) {
    const int*   verts = (const int*)d_in[0];    // [N,3] int32
    const float* feats = (const float*)d_in[1];  // [N,64] fp32
    float*       out   = (float*)d_out;          // [N_VOX*64] fp32

    const int n_pts = in_sizes[0] / 3;           // 1,000,000

    char* w = (char*)d_ws;
    int*  vox        = (int*)w;              w += (size_t)n_pts * 4;
    int*  sorted_idx = (int*)w;              w += (size_t)n_pts * 4;
    int*  counts     = (int*)w;              w += (size_t)N_VOX * 4;
    int2* meta       = (int2*)w;             w += (size_t)N_VOX * 8;
    int*  gmut       = (int*)w;              w += (size_t)N_VOX * 4;
    int*  bsum       = (int*)w;

    hipMemsetAsync(counts, 0, (size_t)N_VOX * 4, stream);

    {   // histogram + voxel ids (4 points/thread)
        const int block = 256;
        const int nthr  = (n_pts + 3) / 4;
        const int grid  = (nthr + block - 1) / block;
        k_hist<<<grid, block, 0, stream>>>(verts, vox, counts, n_pts);
    }
    // hierarchical exclusive scan -> meta(start,end) + mutable offsets
    k_bsum<<<256, 256, 0, stream>>>(counts, bsum);
    k_scan2<<<1, 256, 0, stream>>>(bsum);
    k_scanfinal<<<N_VOX / 1024, 1024, 0, stream>>>(counts, bsum, meta, gmut);

    {   // scatter indices (4 points/thread)
        const int block = 256;
        const int nthr  = (n_pts + 3) / 4;
        const int grid  = (nthr + block - 1) / block;
        k_scatter_idx<<<grid, block, 0, stream>>>(vox, gmut, sorted_idx, n_pts);
    }
    {   // gather max: 16 lanes per voxel, float4 per lane
        const int block = 256;
        const int grid  = (N_VOX * 16) / block;  // 16384
        k_gather<<<grid, block, 0, stream>>>(sorted_idx, meta,
                                             (const float4*)feats, (float4*)out);
    }
}